// Round 1
// baseline (443.862 us; speedup 1.0000x reference)
//
#include <hip/hip_runtime.h>
#include <math.h>

#define CIN   128
#define COUT  128
#define HH    64
#define WWID  64
#define BB    8
#define KKT   9
#define NSTAT 32768.0f   // B*H*W per-channel count

// ---------------- ws layout (floats) ----------------
// wdp   : 9*128*128 = 147456   (w_def repacked [k][c][oc])
// offs  : 8*18*64*64 = 589824  (offset conv output)
// sums  : 128
// sumsq : 128
// scsh  : 256  (scale | shift)

__global__ __launch_bounds__(256) void repack_wdef_k(const float* __restrict__ w_def,
                                                     float* __restrict__ wdp) {
    int i = blockIdx.x * 256 + threadIdx.x;
    if (i < KKT * CIN * COUT) {
        int oc = i & 127;
        int c  = (i >> 7) & 127;
        int k  = i >> 14;
        wdp[i] = w_def[(oc * CIN + c) * KKT + k];
    }
}

// One block per (b,h). 256 threads = 4 c-groups x 64 w. 18 accumulators/thread.
__global__ __launch_bounds__(256) void offset_conv_k(const float* __restrict__ x,
                                                     const float* __restrict__ w_off,
                                                     float* __restrict__ offs) {
    __shared__ float red[18 * 4 * 64];  // [oc][cg][w]
    const int t  = threadIdx.x;
    const int bh = blockIdx.x;
    const int b  = bh >> 6;
    const int h  = bh & 63;
    const int w  = t & 63;
    const int cg = __builtin_amdgcn_readfirstlane(t >> 6);  // wave-uniform c-group

    float acc[18];
#pragma unroll
    for (int o = 0; o < 18; o++) acc[o] = 0.f;

    const float* xb = x + b * CIN * HH * WWID;
    for (int ci = 0; ci < 32; ci++) {
        int c = cg * 32 + ci;
        const float* xc = xb + c * HH * WWID;
#pragma unroll
        for (int ky = 0; ky < 3; ky++) {
            int y = h + ky - 1;
            if ((unsigned)y < 64u) {
                const float* xr = xc + y * WWID;
#pragma unroll
                for (int kx = 0; kx < 3; kx++) {
                    int xx = w + kx - 1;
                    float xv = ((unsigned)xx < 64u) ? xr[xx] : 0.f;
#pragma unroll
                    for (int oc = 0; oc < 18; oc++) {
                        acc[oc] = fmaf(xv, w_off[((oc * CIN + c) * 3 + ky) * 3 + kx], acc[oc]);
                    }
                }
            }
        }
    }
#pragma unroll
    for (int oc = 0; oc < 18; oc++) red[(oc * 4 + cg) * 64 + w] = acc[oc];
    __syncthreads();
    for (int i = t; i < 18 * 64; i += 256) {
        int oc = i >> 6, ww = i & 63;
        float s = red[(oc * 4 + 0) * 64 + ww] + red[(oc * 4 + 1) * 64 + ww] +
                  red[(oc * 4 + 2) * 64 + ww] + red[(oc * 4 + 3) * 64 + ww];
        offs[((b * 18 + oc) * 64 + h) * 64 + ww] = s;
    }
}

// One block per (b,h). Wave wv owns oc in [wv*32, wv*32+32), lanes = w.
__global__ __launch_bounds__(256) void deform_main_k(const float* __restrict__ x,
                                                     const float* __restrict__ offs,
                                                     const float* __restrict__ wdp,
                                                     const float* __restrict__ b_def,
                                                     float* __restrict__ out,
                                                     float* __restrict__ sums,
                                                     float* __restrict__ sumsq) {
    __shared__ float samp[CIN * 64];     // 32 KB: [c][w]
    __shared__ int   toff[KKT * 64 * 4]; // 9 KB: clamped flat spatial idx per tap
    __shared__ float twt[KKT * 64 * 4];  // 9 KB: validity-folded bilinear weight

    const int t    = threadIdx.x;
    const int bh   = blockIdx.x;
    const int b    = bh >> 6;
    const int h    = bh & 63;
    const int lane = t & 63;
    const int ocg  = __builtin_amdgcn_readfirstlane(t >> 6);
    const int oc0  = ocg * 32;

    // Phase 1: bilinear tap tables for this (b,h) row: 9 k x 64 w
    for (int i = t; i < KKT * 64; i += 256) {
        int k = i >> 6, w = i & 63;
        float dy = offs[((b * 18 + 2 * k) * 64 + h) * 64 + w];
        float dx = offs[((b * 18 + 2 * k + 1) * 64 + h) * 64 + w];
        int ky = k / 3, kx = k - ky * 3;
        float ys = (float)(h - 1 + ky) + dy;
        float xs = (float)(w - 1 + kx) + dx;
        float y0f = floorf(ys), x0f = floorf(xs);
        float wy = ys - y0f, wx = xs - x0f;
        int iy0 = (int)y0f, ix0 = (int)x0f;
        int iy1 = iy0 + 1, ix1 = ix0 + 1;
        int cy0 = min(max(iy0, 0), 63), cy1 = min(max(iy1, 0), 63);
        int cx0 = min(max(ix0, 0), 63), cx1 = min(max(ix1, 0), 63);
        bool vy0 = (iy0 >= 0) && (iy0 < 64);
        bool vy1 = (iy1 >= 0) && (iy1 < 64);
        bool vx0 = (ix0 >= 0) && (ix0 < 64);
        bool vx1 = (ix1 >= 0) && (ix1 < 64);
        int base = i * 4;
        toff[base + 0] = cy0 * 64 + cx0; twt[base + 0] = (vy0 && vx0) ? (1.f - wy) * (1.f - wx) : 0.f;
        toff[base + 1] = cy0 * 64 + cx1; twt[base + 1] = (vy0 && vx1) ? (1.f - wy) * wx : 0.f;
        toff[base + 2] = cy1 * 64 + cx0; twt[base + 2] = (vy1 && vx0) ? wy * (1.f - wx) : 0.f;
        toff[base + 3] = cy1 * 64 + cx1; twt[base + 3] = (vy1 && vx1) ? wy * wx : 0.f;
    }
    __syncthreads();

    float acc[32];
#pragma unroll
    for (int j = 0; j < 32; j++) acc[j] = 0.f;

    const float* xb = x + b * CIN * HH * WWID;

    for (int k = 0; k < KKT; k++) {
        // Phase 2: stage samp[c][w] for all 128 c (each wave samples 32 c's)
        int tb = (k * 64 + lane) * 4;
        int4   o  = *(const int4*)&toff[tb];
        float4 wt = *(const float4*)&twt[tb];
#pragma unroll 4
        for (int i = 0; i < 32; i++) {
            int c = ocg * 32 + i;
            const float* xc = xb + c * 4096;
            samp[c * 64 + lane] = wt.x * xc[o.x] + wt.y * xc[o.y] + wt.z * xc[o.z] + wt.w * xc[o.w];
        }
        __syncthreads();

        // Phase 3: rank-1 updates over c; weight reads are wave-uniform (scalar)
        const float* wkbase = wdp + (k * CIN) * COUT + oc0;
#pragma unroll 2
        for (int c = 0; c < CIN; c++) {
            float v = samp[c * 64 + lane];
            const float4* w4 = (const float4*)(wkbase + c * COUT);
#pragma unroll
            for (int jj = 0; jj < 8; jj++) {
                float4 wv4 = w4[jj];
                acc[jj * 4 + 0] = fmaf(v, wv4.x, acc[jj * 4 + 0]);
                acc[jj * 4 + 1] = fmaf(v, wv4.y, acc[jj * 4 + 1]);
                acc[jj * 4 + 2] = fmaf(v, wv4.z, acc[jj * 4 + 2]);
                acc[jj * 4 + 3] = fmaf(v, wv4.w, acc[jj * 4 + 3]);
            }
        }
        __syncthreads();
    }

    // Epilogue: bias, store pre-BN, butterfly-reduce sum/sumsq over 64 lanes (w)
    float my_s = 0.f, my_q = 0.f;
    const int outbase = b * COUT * 4096 + h * 64 + lane;
#pragma unroll
    for (int j = 0; j < 32; j++) {
        int oc = oc0 + j;
        float v = acc[j] + b_def[oc];
        out[outbase + oc * 4096] = v;
        float s = v, q = v * v;
#pragma unroll
        for (int d = 1; d < 64; d <<= 1) {
            s += __shfl_xor(s, d, 64);
            q += __shfl_xor(q, d, 64);
        }
        if (lane == j) { my_s = s; my_q = q; }
    }
    if (lane < 32) {
        atomicAdd(&sums[oc0 + lane], my_s);
        atomicAdd(&sumsq[oc0 + lane], my_q);
    }
}

__global__ void bn_finalize_k(const float* __restrict__ sums, const float* __restrict__ sumsq,
                              const float* __restrict__ gamma, const float* __restrict__ beta,
                              float* __restrict__ scsh) {
    int oc = threadIdx.x;
    const float invN = 1.f / NSTAT;
    float m = sums[oc] * invN;
    float v = fmaf(-m, m, sumsq[oc] * invN);
    float sc = gamma[oc] * rsqrtf(v + 1e-5f);
    scsh[oc]       = sc;
    scsh[128 + oc] = beta[oc] - m * sc;
}

__global__ __launch_bounds__(256) void bn_silu_k(float* __restrict__ out,
                                                 const float* __restrict__ scsh) {
    int i = blockIdx.x * 256 + threadIdx.x;  // float4 index, 1048576 total
    float4 v = ((float4*)out)[i];
    int oc = ((i * 4) >> 12) & 127;
    float sc = scsh[oc], sh = scsh[128 + oc];
    float z0 = v.x * sc + sh;
    float z1 = v.y * sc + sh;
    float z2 = v.z * sc + sh;
    float z3 = v.w * sc + sh;
    v.x = z0 / (1.f + __expf(-z0));
    v.y = z1 / (1.f + __expf(-z1));
    v.z = z2 / (1.f + __expf(-z2));
    v.w = z3 / (1.f + __expf(-z3));
    ((float4*)out)[i] = v;
}

extern "C" void kernel_launch(void* const* d_in, const int* in_sizes, int n_in,
                              void* d_out, int out_size, void* d_ws, size_t ws_size,
                              hipStream_t stream) {
    const float* x     = (const float*)d_in[0];
    const float* w_off = (const float*)d_in[1];
    const float* w_def = (const float*)d_in[2];
    const float* b_def = (const float*)d_in[3];
    const float* gamma = (const float*)d_in[4];
    const float* beta  = (const float*)d_in[5];
    float* out = (float*)d_out;

    float* wdp   = (float*)d_ws;
    float* offs  = wdp + 147456;
    float* sums  = offs + 589824;
    float* sumsq = sums + 128;
    float* scsh  = sumsq + 128;

    hipMemsetAsync(sums, 0, 256 * sizeof(float), stream);
    repack_wdef_k<<<576, 256, 0, stream>>>(w_def, wdp);
    offset_conv_k<<<512, 256, 0, stream>>>(x, w_off, offs);
    deform_main_k<<<512, 256, 0, stream>>>(x, offs, wdp, b_def, out, sums, sumsq);
    bn_finalize_k<<<1, 128, 0, stream>>>(sums, sumsq, gamma, beta, scsh);
    bn_silu_k<<<4096, 256, 0, stream>>>(out, scsh);
}

// Round 2
// 312.464 us; speedup vs baseline: 1.4205x; 1.4205x over previous
//
#include <hip/hip_runtime.h>
#include <math.h>

#define CIN   128
#define COUT  128
#define HH    64
#define WWID  64
#define BB    8
#define KKT   9
#define NSTAT 32768.0f   // B*H*W per-channel count

// ---------------- ws layout (floats) ----------------
// wdp   : 9*128*128 = 147456   (w_def repacked [k][c][oc])
// offs  : 8*18*64*64 = 589824  (offset conv output)
// sums  : 128
// sumsq : 128
// scsh  : 256  (scale | shift)

__global__ __launch_bounds__(256) void repack_wdef_k(const float* __restrict__ w_def,
                                                     float* __restrict__ wdp) {
    int i = blockIdx.x * 256 + threadIdx.x;
    if (i < KKT * CIN * COUT) {
        int oc = i & 127;
        int c  = (i >> 7) & 127;
        int k  = i >> 14;
        wdp[i] = w_def[(oc * CIN + c) * KKT + k];
    }
}

// One block per (b,h), XCD-swizzled. 512 threads = 8 c-groups x 64 w.
__global__ __launch_bounds__(512) void offset_conv_k(const float* __restrict__ x,
                                                     const float* __restrict__ w_off,
                                                     float* __restrict__ offs) {
    __shared__ float red[18 * 8 * 64];  // [oc][cg][w] = 36 KB
    const int t  = threadIdx.x;
    const int bh = blockIdx.x;
    const int b  = bh >> 6;
    const int j  = bh & 63;
    const int h  = ((j & 7) << 3) | (j >> 3);   // XCD-locality swizzle
    const int w  = t & 63;
    const int cg = __builtin_amdgcn_readfirstlane(t >> 6);  // 0..7, 16 c each

    float acc[18];
#pragma unroll
    for (int o = 0; o < 18; o++) acc[o] = 0.f;

    const float* xb = x + b * CIN * HH * WWID;
    for (int ci = 0; ci < 16; ci++) {
        int c = cg * 16 + ci;
        const float* xc = xb + c * HH * WWID;
        float xv[9];
#pragma unroll
        for (int ky = 0; ky < 3; ky++) {
            int y = h + ky - 1;
            bool vy = (unsigned)y < 64u;
#pragma unroll
            for (int kx = 0; kx < 3; kx++) {
                int xx = w + kx - 1;
                bool vx = (unsigned)xx < 64u;
                xv[ky * 3 + kx] = (vy && vx) ? xc[y * WWID + xx] : 0.f;
            }
        }
        const float* wo = w_off + c * 9;   // stride between oc: 128*9
#pragma unroll
        for (int oc = 0; oc < 18; oc++) {
#pragma unroll
            for (int q = 0; q < 9; q++) {
                acc[oc] = fmaf(xv[q], wo[oc * (CIN * 9) + q], acc[oc]);
            }
        }
    }
#pragma unroll
    for (int oc = 0; oc < 18; oc++) red[(oc * 8 + cg) * 64 + w] = acc[oc];
    __syncthreads();
    for (int i = t; i < 18 * 64; i += 512) {
        int oc = i >> 6, ww = i & 63;
        float s = 0.f;
#pragma unroll
        for (int g = 0; g < 8; g++) s += red[(oc * 8 + g) * 64 + ww];
        offs[((b * 18 + oc) * 64 + h) * 64 + ww] = s;
    }
}

// One block per (b,h), XCD-swizzled. 512 threads = 8 waves.
// Wave wv owns oc in [wv*16, wv*16+16) and gathers c in [wv*16, wv*16+16).
__global__ __launch_bounds__(512) void deform_main_k(const float* __restrict__ x,
                                                     const float* __restrict__ offs,
                                                     const float* __restrict__ wdp,
                                                     const float* __restrict__ b_def,
                                                     float* __restrict__ out,
                                                     float* __restrict__ sums,
                                                     float* __restrict__ sumsq) {
    __shared__ float samp[CIN * 64];     // 32 KB: [c][w]
    __shared__ int   toff[KKT * 64 * 4]; // 9 KB
    __shared__ float twt[KKT * 64 * 4];  // 9 KB

    const int t    = threadIdx.x;
    const int bh   = blockIdx.x;
    const int b    = bh >> 6;
    const int jj_  = bh & 63;
    const int h    = ((jj_ & 7) << 3) | (jj_ >> 3);  // XCD-locality swizzle
    const int lane = t & 63;
    const int ocg  = __builtin_amdgcn_readfirstlane(t >> 6);  // 0..7
    const int oc0  = ocg * 16;

    // Phase 1: bilinear tap tables for this (b,h) row: 9 k x 64 w
    for (int i = t; i < KKT * 64; i += 512) {
        int k = i >> 6, w = i & 63;
        float dy = offs[((b * 18 + 2 * k) * 64 + h) * 64 + w];
        float dx = offs[((b * 18 + 2 * k + 1) * 64 + h) * 64 + w];
        int ky = k / 3, kx = k - ky * 3;
        float ys = (float)(h - 1 + ky) + dy;
        float xs = (float)(w - 1 + kx) + dx;
        float y0f = floorf(ys), x0f = floorf(xs);
        float wy = ys - y0f, wx = xs - x0f;
        int iy0 = (int)y0f, ix0 = (int)x0f;
        int iy1 = iy0 + 1, ix1 = ix0 + 1;
        int cy0 = min(max(iy0, 0), 63), cy1 = min(max(iy1, 0), 63);
        int cx0 = min(max(ix0, 0), 63), cx1 = min(max(ix1, 0), 63);
        bool vy0 = (iy0 >= 0) && (iy0 < 64);
        bool vy1 = (iy1 >= 0) && (iy1 < 64);
        bool vx0 = (ix0 >= 0) && (ix0 < 64);
        bool vx1 = (ix1 >= 0) && (ix1 < 64);
        int base = i * 4;
        toff[base + 0] = cy0 * 64 + cx0; twt[base + 0] = (vy0 && vx0) ? (1.f - wy) * (1.f - wx) : 0.f;
        toff[base + 1] = cy0 * 64 + cx1; twt[base + 1] = (vy0 && vx1) ? (1.f - wy) * wx : 0.f;
        toff[base + 2] = cy1 * 64 + cx0; twt[base + 2] = (vy1 && vx0) ? wy * (1.f - wx) : 0.f;
        toff[base + 3] = cy1 * 64 + cx1; twt[base + 3] = (vy1 && vx1) ? wy * wx : 0.f;
    }
    __syncthreads();

    float acc[16];
#pragma unroll
    for (int q = 0; q < 16; q++) acc[q] = 0.f;

    const float* xb = x + b * CIN * HH * WWID;

    for (int k = 0; k < KKT; k++) {
        // Phase 2: each wave gathers 16 c's for its w=lane
        int tb = (k * 64 + lane) * 4;
        int4   o  = *(const int4*)&toff[tb];
        float4 wt = *(const float4*)&twt[tb];
#pragma unroll 8
        for (int i = 0; i < 16; i++) {
            int c = ocg * 16 + i;
            const float* xc = xb + c * 4096;
            samp[c * 64 + lane] = wt.x * xc[o.x] + wt.y * xc[o.y] + wt.z * xc[o.z] + wt.w * xc[o.w];
        }
        __syncthreads();

        // Phase 3: rank-1 updates over all 128 c; weight reads wave-uniform
        const float* wkbase = wdp + (k * CIN) * COUT + oc0;
#pragma unroll 2
        for (int c = 0; c < CIN; c++) {
            float v = samp[c * 64 + lane];
            const float4* w4 = (const float4*)(wkbase + c * COUT);
#pragma unroll
            for (int q = 0; q < 4; q++) {
                float4 wv4 = w4[q];
                acc[q * 4 + 0] = fmaf(v, wv4.x, acc[q * 4 + 0]);
                acc[q * 4 + 1] = fmaf(v, wv4.y, acc[q * 4 + 1]);
                acc[q * 4 + 2] = fmaf(v, wv4.z, acc[q * 4 + 2]);
                acc[q * 4 + 3] = fmaf(v, wv4.w, acc[q * 4 + 3]);
            }
        }
        __syncthreads();
    }

    // Epilogue: bias, store pre-BN, butterfly-reduce sum/sumsq over 64 lanes (w)
    float my_s = 0.f, my_q = 0.f;
    const int outbase = b * COUT * 4096 + h * 64 + lane;
#pragma unroll
    for (int q = 0; q < 16; q++) {
        int oc = oc0 + q;
        float v = acc[q] + b_def[oc];
        out[outbase + oc * 4096] = v;
        float s = v, sq = v * v;
#pragma unroll
        for (int d = 1; d < 64; d <<= 1) {
            s  += __shfl_xor(s, d, 64);
            sq += __shfl_xor(sq, d, 64);
        }
        if (lane == q) { my_s = s; my_q = sq; }
    }
    if (lane < 16) {
        atomicAdd(&sums[oc0 + lane], my_s);
        atomicAdd(&sumsq[oc0 + lane], my_q);
    }
}

__global__ void bn_finalize_k(const float* __restrict__ sums, const float* __restrict__ sumsq,
                              const float* __restrict__ gamma, const float* __restrict__ beta,
                              float* __restrict__ scsh) {
    int oc = threadIdx.x;
    const float invN = 1.f / NSTAT;
    float m = sums[oc] * invN;
    float v = fmaf(-m, m, sumsq[oc] * invN);
    float sc = gamma[oc] * rsqrtf(v + 1e-5f);
    scsh[oc]       = sc;
    scsh[128 + oc] = beta[oc] - m * sc;
}

__global__ __launch_bounds__(256) void bn_silu_k(float* __restrict__ out,
                                                 const float* __restrict__ scsh) {
    int i = blockIdx.x * 256 + threadIdx.x;  // float4 index, 1048576 total
    float4 v = ((float4*)out)[i];
    int oc = ((i * 4) >> 12) & 127;
    float sc = scsh[oc], sh = scsh[128 + oc];
    float z0 = v.x * sc + sh;
    float z1 = v.y * sc + sh;
    float z2 = v.z * sc + sh;
    float z3 = v.w * sc + sh;
    v.x = z0 / (1.f + __expf(-z0));
    v.y = z1 / (1.f + __expf(-z1));
    v.z = z2 / (1.f + __expf(-z2));
    v.w = z3 / (1.f + __expf(-z3));
    ((float4*)out)[i] = v;
}

extern "C" void kernel_launch(void* const* d_in, const int* in_sizes, int n_in,
                              void* d_out, int out_size, void* d_ws, size_t ws_size,
                              hipStream_t stream) {
    const float* x     = (const float*)d_in[0];
    const float* w_off = (const float*)d_in[1];
    const float* w_def = (const float*)d_in[2];
    const float* b_def = (const float*)d_in[3];
    const float* gamma = (const float*)d_in[4];
    const float* beta  = (const float*)d_in[5];
    float* out = (float*)d_out;

    float* wdp   = (float*)d_ws;
    float* offs  = wdp + 147456;
    float* sums  = offs + 589824;
    float* sumsq = sums + 128;
    float* scsh  = sumsq + 128;

    hipMemsetAsync(sums, 0, 256 * sizeof(float), stream);
    repack_wdef_k<<<576, 256, 0, stream>>>(w_def, wdp);
    offset_conv_k<<<512, 512, 0, stream>>>(x, w_off, offs);
    deform_main_k<<<512, 512, 0, stream>>>(x, offs, wdp, b_def, out, sums, sumsq);
    bn_finalize_k<<<1, 128, 0, stream>>>(sums, sumsq, gamma, beta, scsh);
    bn_silu_k<<<4096, 256, 0, stream>>>(out, scsh);
}

// Round 3
// 242.237 us; speedup vs baseline: 1.8323x; 1.2899x over previous
//
#include <hip/hip_runtime.h>
#include <math.h>

#define CIN   128
#define COUT  128
#define KKT   9
#define NSTAT 32768.0f   // B*H*W per-channel count

typedef __attribute__((ext_vector_type(8))) short bf16x8;
typedef __attribute__((ext_vector_type(4))) float f32x4;

__device__ inline unsigned short f2bf(float f) {
    union { float f; unsigned u; } v; v.f = f;
    unsigned r = v.u + 0x7fffu + ((v.u >> 16) & 1u);
    return (unsigned short)(r >> 16);
}

// ---------------- ws layout ----------------
// wb    : 9*128*128 bf16 (147456 ushort = 73728 float slots)  [oc][kt*128+c]
// offs  : 8*18*64*64 float
// sums  : 128 | sumsq : 128 | scsh : 256

__global__ __launch_bounds__(256) void repack_wdef_k(const float* __restrict__ w_def,
                                                     unsigned short* __restrict__ wb) {
    int i = blockIdx.x * 256 + threadIdx.x;   // grid covers exactly 147456
    int oc = i / 1152;
    int r  = i - oc * 1152;
    int kt = r >> 7;
    int c  = r & 127;
    wb[i] = f2bf(w_def[(oc * CIN + c) * 9 + kt]);
}

// One block per (b,h), XCD-swizzled. 512 threads = 8 c-groups x 64 w.
__global__ __launch_bounds__(512) void offset_conv_k(const float* __restrict__ x,
                                                     const float* __restrict__ w_off,
                                                     float* __restrict__ offs) {
    __shared__ float red[18 * 8 * 64];
    const int t  = threadIdx.x;
    const int bh = blockIdx.x;
    const int b  = bh >> 6;
    const int j  = bh & 63;
    const int h  = ((j & 7) << 3) | (j >> 3);
    const int w  = t & 63;
    const int cg = __builtin_amdgcn_readfirstlane(t >> 6);

    float acc[18];
#pragma unroll
    for (int o = 0; o < 18; o++) acc[o] = 0.f;

    const float* xb = x + b * CIN * 4096;
    for (int ci = 0; ci < 16; ci++) {
        int c = cg * 16 + ci;
        const float* xc = xb + c * 4096;
        float xv[9];
#pragma unroll
        for (int ky = 0; ky < 3; ky++) {
            int y = h + ky - 1;
            bool vy = (unsigned)y < 64u;
#pragma unroll
            for (int kx = 0; kx < 3; kx++) {
                int xx = w + kx - 1;
                bool vx = (unsigned)xx < 64u;
                xv[ky * 3 + kx] = (vy && vx) ? xc[y * 64 + xx] : 0.f;
            }
        }
        const float* wo = w_off + c * 9;
#pragma unroll
        for (int oc = 0; oc < 18; oc++) {
#pragma unroll
            for (int q = 0; q < 9; q++) {
                acc[oc] = fmaf(xv[q], wo[oc * (CIN * 9) + q], acc[oc]);
            }
        }
    }
#pragma unroll
    for (int oc = 0; oc < 18; oc++) red[(oc * 8 + cg) * 64 + w] = acc[oc];
    __syncthreads();
    for (int i = t; i < 18 * 64; i += 512) {
        int oc = i >> 6, ww = i & 63;
        float s = 0.f;
#pragma unroll
        for (int g = 0; g < 8; g++) s += red[(oc * 8 + g) * 64 + ww];
        offs[((b * 18 + oc) * 64 + h) * 64 + ww] = s;
    }
}

// One block per (b,h), XCD-swizzled. 512 threads = 8 waves.
// Wave wv: M-tiles {2*(wv>>1), 2*(wv>>1)+1} (oc, 16 each), N-tiles {2*(wv&1), 2*(wv&1)+1} (w).
// MFMA 16x16x32 bf16. A = W[oc][K], B = samp[w][c] (LDS, bf16, group-XOR swizzle).
__global__ __launch_bounds__(512) void deform_main_k(const float* __restrict__ x,
                                                     const float* __restrict__ offs,
                                                     const unsigned short* __restrict__ wb,
                                                     const float* __restrict__ b_def,
                                                     float* __restrict__ out) {
    __shared__ __align__(16) unsigned short samp[64 * 128]; // [w][c] bf16, 16 KB
    __shared__ int   toff[KKT * 64 * 4]; // 9 KB
    __shared__ float twt[KKT * 64 * 4];  // 9 KB

    const int t    = threadIdx.x;
    const int bh   = blockIdx.x;
    const int b    = bh >> 6;
    const int j_   = bh & 63;
    const int h    = ((j_ & 7) << 3) | (j_ >> 3);   // XCD-locality swizzle
    const int lane = t & 63;
    const int wv   = __builtin_amdgcn_readfirstlane(t >> 6);  // 0..7
    const int m0   = wv >> 1;    // 0..3
    const int n0   = wv & 1;     // 0..1
    const int quad = lane >> 4;
    const int lo   = lane & 15;

    // Phase 1: bilinear tap tables for this (b,h) row
    for (int i = t; i < KKT * 64; i += 512) {
        int k = i >> 6, w = i & 63;
        float dy = offs[((b * 18 + 2 * k) * 64 + h) * 64 + w];
        float dx = offs[((b * 18 + 2 * k + 1) * 64 + h) * 64 + w];
        int ky = k / 3, kx = k - ky * 3;
        float ys = (float)(h - 1 + ky) + dy;
        float xs = (float)(w - 1 + kx) + dx;
        float y0f = floorf(ys), x0f = floorf(xs);
        float wy = ys - y0f, wx = xs - x0f;
        int iy0 = (int)y0f, ix0 = (int)x0f;
        int iy1 = iy0 + 1, ix1 = ix0 + 1;
        int cy0 = min(max(iy0, 0), 63), cy1 = min(max(iy1, 0), 63);
        int cx0 = min(max(ix0, 0), 63), cx1 = min(max(ix1, 0), 63);
        bool vy0 = (iy0 >= 0) && (iy0 < 64);
        bool vy1 = (iy1 >= 0) && (iy1 < 64);
        bool vx0 = (ix0 >= 0) && (ix0 < 64);
        bool vx1 = (ix1 >= 0) && (ix1 < 64);
        int base = i * 4;
        toff[base + 0] = cy0 * 64 + cx0; twt[base + 0] = (vy0 && vx0) ? (1.f - wy) * (1.f - wx) : 0.f;
        toff[base + 1] = cy0 * 64 + cx1; twt[base + 1] = (vy0 && vx1) ? (1.f - wy) * wx : 0.f;
        toff[base + 2] = cy1 * 64 + cx0; twt[base + 2] = (vy1 && vx0) ? wy * (1.f - wx) : 0.f;
        toff[base + 3] = cy1 * 64 + cx1; twt[base + 3] = (vy1 && vx1) ? wy * wx : 0.f;
    }

    f32x4 acc[2][2];
#pragma unroll
    for (int i = 0; i < 2; i++)
#pragma unroll
        for (int j = 0; j < 2; j++)
#pragma unroll
            for (int r = 0; r < 4; r++) acc[i][j][r] = 0.f;

    const float* xb = x + b * CIN * 4096;
    const unsigned short* wrow0 = wb + (2 * m0 * 16 + lo) * 1152 + quad * 8;
    const unsigned short* wrow1 = wrow0 + 16 * 1152;

    __syncthreads();  // tap tables ready

    for (int kt = 0; kt < KKT; kt++) {
        // A-fragment prefetch for this tap (global, L2-resident; latency overlaps phase 2)
        bf16x8 afr[2][4];
#pragma unroll
        for (int ch = 0; ch < 4; ch++) {
            afr[0][ch] = *(const bf16x8*)(wrow0 + kt * 128 + ch * 32);
            afr[1][ch] = *(const bf16x8*)(wrow1 + kt * 128 + ch * 32);
        }

        // Phase 2: gather 16 c's for w=lane, pack bf16, 2 swizzled b128 LDS writes
        int tb = (kt * 64 + lane) * 4;
        int4   o  = *(const int4*)&toff[tb];
        float4 wt = *(const float4*)&twt[tb];
#pragma unroll
        for (int g2 = 0; g2 < 2; g2++) {
            int g = wv * 2 + g2;
            unsigned short pk[8];
#pragma unroll
            for (int jj = 0; jj < 8; jj++) {
                const float* xc = xb + (g * 8 + jj) * 4096;
                float s = wt.x * xc[o.x] + wt.y * xc[o.y] + wt.z * xc[o.z] + wt.w * xc[o.w];
                pk[jj] = f2bf(s);
            }
            *(bf16x8*)&samp[lane * 128 + ((g ^ lo) << 3)] = *(const bf16x8*)pk;
        }
        __syncthreads();

        // Phase 3: 4 chunks x (2 B ds_read_b128 + 4 MFMA)
#pragma unroll
        for (int ch = 0; ch < 4; ch++) {
            int g = ch * 4 + quad;
            bf16x8 bfr[2];
#pragma unroll
            for (int nt2 = 0; nt2 < 2; nt2++) {
                int wrow = (2 * n0 + nt2) * 16 + lo;
                bfr[nt2] = *(const bf16x8*)&samp[wrow * 128 + ((g ^ lo) << 3)];
            }
#pragma unroll
            for (int mt2 = 0; mt2 < 2; mt2++)
#pragma unroll
                for (int nt2 = 0; nt2 < 2; nt2++)
                    acc[mt2][nt2] = __builtin_amdgcn_mfma_f32_16x16x32_bf16(
                        afr[mt2][ch], bfr[nt2], acc[mt2][nt2], 0, 0, 0);
        }
        __syncthreads();
    }

    // Epilogue: bias + store pre-BN (C/D layout: col=lane&15 -> w, row=quad*4+reg -> oc)
    float* ob = out + (b * COUT) * 4096 + h * 64;
#pragma unroll
    for (int mt2 = 0; mt2 < 2; mt2++) {
        int ocb = (2 * m0 + mt2) * 16 + quad * 4;
#pragma unroll
        for (int nt2 = 0; nt2 < 2; nt2++) {
            int w_ = (2 * n0 + nt2) * 16 + lo;
#pragma unroll
            for (int r = 0; r < 4; r++) {
                int oc = ocb + r;
                ob[oc * 4096 + w_] = acc[mt2][nt2][r] + b_def[oc];
            }
        }
    }
}

// Per-channel sum/sumsq over (B,H,W). One block per oc.
__global__ __launch_bounds__(256) void bn_stats_k(const float* __restrict__ out,
                                                  float* __restrict__ sums,
                                                  float* __restrict__ sumsq) {
    int oc = blockIdx.x, t = threadIdx.x;
    float s = 0.f, q = 0.f;
    for (int b = 0; b < 8; b++) {
        const float4* p = (const float4*)(out + (b * COUT + oc) * 4096);
        for (int i = t; i < 1024; i += 256) {
            float4 v = p[i];
            s += v.x + v.y + v.z + v.w;
            q += v.x * v.x + v.y * v.y + v.z * v.z + v.w * v.w;
        }
    }
#pragma unroll
    for (int d = 1; d < 64; d <<= 1) { s += __shfl_xor(s, d, 64); q += __shfl_xor(q, d, 64); }
    __shared__ float rs[4], rq[4];
    if ((t & 63) == 0) { rs[t >> 6] = s; rq[t >> 6] = q; }
    __syncthreads();
    if (t == 0) {
        sums[oc]  = rs[0] + rs[1] + rs[2] + rs[3];
        sumsq[oc] = rq[0] + rq[1] + rq[2] + rq[3];
    }
}

__global__ void bn_finalize_k(const float* __restrict__ sums, const float* __restrict__ sumsq,
                              const float* __restrict__ gamma, const float* __restrict__ beta,
                              float* __restrict__ scsh) {
    int oc = threadIdx.x;
    const float invN = 1.f / NSTAT;
    float m = sums[oc] * invN;
    float v = fmaf(-m, m, sumsq[oc] * invN);
    float sc = gamma[oc] * rsqrtf(v + 1e-5f);
    scsh[oc]       = sc;
    scsh[128 + oc] = beta[oc] - m * sc;
}

__global__ __launch_bounds__(256) void bn_silu_k(float* __restrict__ out,
                                                 const float* __restrict__ scsh) {
    int i = blockIdx.x * 256 + threadIdx.x;
    float4 v = ((float4*)out)[i];
    int oc = ((i * 4) >> 12) & 127;
    float sc = scsh[oc], sh = scsh[128 + oc];
    float z0 = v.x * sc + sh;
    float z1 = v.y * sc + sh;
    float z2 = v.z * sc + sh;
    float z3 = v.w * sc + sh;
    v.x = z0 / (1.f + __expf(-z0));
    v.y = z1 / (1.f + __expf(-z1));
    v.z = z2 / (1.f + __expf(-z2));
    v.w = z3 / (1.f + __expf(-z3));
    ((float4*)out)[i] = v;
}

extern "C" void kernel_launch(void* const* d_in, const int* in_sizes, int n_in,
                              void* d_out, int out_size, void* d_ws, size_t ws_size,
                              hipStream_t stream) {
    const float* x     = (const float*)d_in[0];
    const float* w_off = (const float*)d_in[1];
    const float* w_def = (const float*)d_in[2];
    const float* b_def = (const float*)d_in[3];
    const float* gamma = (const float*)d_in[4];
    const float* beta  = (const float*)d_in[5];
    float* out = (float*)d_out;

    unsigned short* wb = (unsigned short*)d_ws;
    float* offs  = (float*)d_ws + 73728;
    float* sums  = offs + 589824;
    float* sumsq = sums + 128;
    float* scsh  = sumsq + 128;

    repack_wdef_k<<<576, 256, 0, stream>>>(w_def, wb);
    offset_conv_k<<<512, 512, 0, stream>>>(x, w_off, offs);
    deform_main_k<<<512, 512, 0, stream>>>(x, offs, wb, b_def, out);
    bn_stats_k<<<128, 256, 0, stream>>>(out, sums, sumsq);
    bn_finalize_k<<<1, 128, 0, stream>>>(sums, sumsq, gamma, beta, scsh);
    bn_silu_k<<<4096, 256, 0, stream>>>(out, scsh);
}

// Round 4
// 205.764 us; speedup vs baseline: 2.1571x; 1.1773x over previous
//
#include <hip/hip_runtime.h>
#include <math.h>

#define CIN   128
#define COUT  128
#define KKT   9
#define NSTAT 32768.0f   // B*H*W per-channel count

typedef __attribute__((ext_vector_type(8))) short bf16x8;
typedef __attribute__((ext_vector_type(4))) float f32x4;

__device__ inline unsigned short f2bf(float f) {
    union { float f; unsigned u; } v; v.f = f;
    unsigned r = v.u + 0x7fffu + ((v.u >> 16) & 1u);
    return (unsigned short)(r >> 16);
}
__device__ inline float bflo(unsigned u) { union { unsigned u; float f; } v; v.u = u << 16; return v.f; }
__device__ inline float bfhi(unsigned u) { union { unsigned u; float f; } v; v.u = u & 0xffff0000u; return v.f; }

// barrier that does NOT drain vmcnt -> global prefetch loads stay in flight
#define FAST_BARRIER() asm volatile("s_waitcnt lgkmcnt(0)\n\ts_barrier" ::: "memory")

// ---------------- ws layout ----------------
// wb  : 9*128*128 bf16 = 294912 B       [oc][kt*128+c]
// xp  : 8*128*64*64 uint = 16777216 B   bf16 pair (x[w], x[w+1])
// sums: 128 f | sumsq: 128 f | scsh: 256 f

__global__ __launch_bounds__(256) void prep_xp_k(const float* __restrict__ x,
                                                 unsigned* __restrict__ xp) {
    int i = blockIdx.x * 256 + threadIdx.x;   // 4194304 total
    int w = i & 63;
    float a = x[i];
    float b = (w < 63) ? x[i + 1] : 0.f;
    xp[i] = (unsigned)f2bf(a) | ((unsigned)f2bf(b) << 16);
}

__global__ __launch_bounds__(256) void repack_wdef_k(const float* __restrict__ w_def,
                                                     unsigned short* __restrict__ wb) {
    int i = blockIdx.x * 256 + threadIdx.x;   // 147456 total
    int oc = i / 1152;
    int r  = i - oc * 1152;
    int kt = r >> 7;
    int c  = r & 127;
    wb[i] = f2bf(w_def[(oc * CIN + c) * 9 + kt]);
}

// One block per (b,h), XCD-swizzled. 512 threads = 8 waves.
// Phase 0: offset conv (fused). Phase 1: tap tables. Taps: pipelined gather + MFMA.
__global__ __launch_bounds__(512, 4) void deform_main_k(const unsigned* __restrict__ xp,
                                                        const float* __restrict__ w_off,
                                                        const unsigned short* __restrict__ wb,
                                                        const float* __restrict__ b_def,
                                                        float* __restrict__ out,
                                                        float* __restrict__ sums,
                                                        float* __restrict__ sumsq) {
    // manual LDS layout: red(36864) aliases samp0(16384)+samp1(16384)
    __shared__ __align__(16) unsigned char smem[36864 + 18432 + 4608 + 1024];
    float*          red   = (float*)smem;                       // [18][8][64]
    unsigned short* samp0 = (unsigned short*)smem;              // [64][128] bf16
    unsigned short* samp1 = (unsigned short*)(smem + 16384);
    int*            tab   = (int*)(smem + 36864);               // [9*64][8]
    float*          offl  = (float*)(smem + 36864 + 18432);     // [18][64]
    float*          stat  = (float*)(smem + 36864 + 18432 + 4608); // [256]

    const int t    = threadIdx.x;
    const int bh   = blockIdx.x;
    const int b    = bh >> 6;
    const int j_   = bh & 63;
    const int h    = ((j_ & 7) << 3) | (j_ >> 3);   // XCD-locality swizzle
    const int lane = t & 63;
    const int wv   = __builtin_amdgcn_readfirstlane(t >> 6);  // 0..7
    const int w    = lane;

    if (t < 256) stat[t] = 0.f;

    const unsigned* xpb = xp + b * CIN * 4096;

    // ---------- Phase 0: offset conv for this (b,h): 18 oc x 64 w ----------
    {
        float acc0[18];
#pragma unroll
        for (int o = 0; o < 18; o++) acc0[o] = 0.f;
        for (int ci = 0; ci < 16; ci++) {
            int c = wv * 16 + ci;
            const unsigned* xc = xpb + c * 4096;
            float xv[9];
#pragma unroll
            for (int r = 0; r < 3; r++) {
                int y = h + r - 1;
                bool vy = (unsigned)y < 64u;
                int yc = min(max(y, 0), 63);
                unsigned pA = xc[yc * 64 + max(w - 1, 0)];
                unsigned pB = xc[yc * 64 + min(w + 1, 63)];
                float xm1 = (w == 0)  ? 0.f : bflo(pA);
                float x0  = (w == 0)  ? bflo(pA) : bfhi(pA);
                float xq1 = (w == 63) ? 0.f : ((w == 0) ? bfhi(pA) : bflo(pB));
                if (!vy) { xm1 = 0.f; x0 = 0.f; xq1 = 0.f; }
                xv[r * 3 + 0] = xm1; xv[r * 3 + 1] = x0; xv[r * 3 + 2] = xq1;
            }
            const float* wo = w_off + c * 9;
#pragma unroll
            for (int oc = 0; oc < 18; oc++) {
#pragma unroll
                for (int q = 0; q < 9; q++)
                    acc0[oc] = fmaf(xv[q], wo[oc * 1152 + q], acc0[oc]);
            }
        }
#pragma unroll
        for (int oc = 0; oc < 18; oc++) red[(oc * 8 + wv) * 64 + w] = acc0[oc];
    }
    __syncthreads();
    for (int i = t; i < 18 * 64; i += 512) {
        int oc = i >> 6, ww = i & 63;
        float s = 0.f;
#pragma unroll
        for (int g = 0; g < 8; g++) s += red[(oc * 8 + g) * 64 + ww];
        offl[oc * 64 + ww] = s;
    }
    __syncthreads();

    // ---------- Phase 1: tap tables {o0,o1,wy0,wy1,wa,wb} ----------
    for (int i = t; i < KKT * 64; i += 512) {
        int k = i >> 6, w2 = i & 63;
        float dy = offl[(2 * k) * 64 + w2];
        float dx = offl[(2 * k + 1) * 64 + w2];
        int ky = k / 3, kx = k - ky * 3;
        float ys = (float)(h - 1 + ky) + dy;
        float xs = (float)(w2 - 1 + kx) + dx;
        float y0f = floorf(ys), x0f = floorf(xs);
        float wyf = ys - y0f, wxf = xs - x0f;
        int iy0 = (int)y0f, ix0 = (int)x0f;
        int cy0 = min(max(iy0, 0), 63), cy1 = min(max(iy0 + 1, 0), 63);
        float wy0 = (iy0 >= 0 && iy0 < 64) ? (1.f - wyf) : 0.f;
        float wy1 = (iy0 + 1 >= 0 && iy0 + 1 < 64) ? wyf : 0.f;
        int px = min(max(ix0, 0), 63);
        bool v0 = (ix0 >= 0 && ix0 < 64);
        bool v1 = (ix0 + 1 >= 0 && ix0 + 1 < 64);
        bool shift = (ix0 == -1);
        float wa  = shift ? wxf : (v0 ? (1.f - wxf) : 0.f);
        float wbv = shift ? 0.f : (v1 ? wxf : 0.f);
        int base = i * 8;
        tab[base + 0] = cy0 * 64 + px;
        tab[base + 1] = cy1 * 64 + px;
        ((float*)tab)[base + 2] = wy0;
        ((float*)tab)[base + 3] = wy1;
        ((float*)tab)[base + 4] = wa;
        ((float*)tab)[base + 5] = wbv;
    }
    __syncthreads();

    // ---------- Tap loop: pipelined gather + double-buffered MFMA ----------
    const int m0 = wv >> 1, n0 = wv & 1, quad = lane >> 4, lo = lane & 15;
    f32x4 acc[2][2];
#pragma unroll
    for (int i = 0; i < 2; i++)
#pragma unroll
        for (int j = 0; j < 2; j++)
#pragma unroll
            for (int r = 0; r < 4; r++) acc[i][j][r] = 0.f;

    const unsigned short* wrow0 = wb + (2 * m0 * 16 + lo) * 1152 + quad * 8;
    const unsigned short* wrow1 = wrow0 + 16 * 1152;

    unsigned rg[32];
    int o0, o1; float wy0, wy1, wa, wbv;
    {   // prefetch tap 0
        int bse = (0 * 64 + lane) * 8;
        o0 = tab[bse]; o1 = tab[bse + 1];
        wy0 = ((float*)tab)[bse + 2]; wy1 = ((float*)tab)[bse + 3];
        wa  = ((float*)tab)[bse + 4]; wbv = ((float*)tab)[bse + 5];
#pragma unroll
        for (int ci = 0; ci < 16; ci++) {
            const unsigned* xc = xpb + (wv * 16 + ci) * 4096;
            rg[2 * ci]     = xc[o0];
            rg[2 * ci + 1] = xc[o1];
        }
    }

    for (int kt = 0; kt < KKT; kt++) {
        unsigned short* sb = (kt & 1) ? samp1 : samp0;
        // compute samp for tap kt from rg (consumes rg + current table regs)
#pragma unroll
        for (int g2 = 0; g2 < 2; g2++) {
            unsigned short pk[8];
#pragma unroll
            for (int jj = 0; jj < 8; jj++) {
                int ci = g2 * 8 + jj;
                unsigned u0 = rg[2 * ci], u1 = rg[2 * ci + 1];
                float r0 = wa * bflo(u0) + wbv * bfhi(u0);
                float r1 = wa * bflo(u1) + wbv * bfhi(u1);
                pk[jj] = f2bf(wy0 * r0 + wy1 * r1);
            }
            int g = wv * 2 + g2;
            *(bf16x8*)&sb[lane * 128 + ((g ^ lo) << 3)] = *(const bf16x8*)pk;
        }
        // prefetch tap kt+1 (loads stay in flight across the barrier + MFMA)
        if (kt < KKT - 1) {
            int bse = ((kt + 1) * 64 + lane) * 8;
            o0 = tab[bse]; o1 = tab[bse + 1];
            wy0 = ((float*)tab)[bse + 2]; wy1 = ((float*)tab)[bse + 3];
            wa  = ((float*)tab)[bse + 4]; wbv = ((float*)tab)[bse + 5];
#pragma unroll
            for (int ci = 0; ci < 16; ci++) {
                const unsigned* xc = xpb + (wv * 16 + ci) * 4096;
                rg[2 * ci]     = xc[o0];
                rg[2 * ci + 1] = xc[o1];
            }
        }
        FAST_BARRIER();   // lgkmcnt(0) + s_barrier, vmcnt NOT drained
        // MFMA phase: 4 chunks x (2 A global + 2 B ds_read_b128 + 4 MFMA)
#pragma unroll
        for (int ch = 0; ch < 4; ch++) {
            bf16x8 af0 = *(const bf16x8*)(wrow0 + kt * 128 + ch * 32);
            bf16x8 af1 = *(const bf16x8*)(wrow1 + kt * 128 + ch * 32);
            int g = ch * 4 + quad;
            bf16x8 bf0 = *(const bf16x8*)&sb[((2 * n0 + 0) * 16 + lo) * 128 + ((g ^ lo) << 3)];
            bf16x8 bf1 = *(const bf16x8*)&sb[((2 * n0 + 1) * 16 + lo) * 128 + ((g ^ lo) << 3)];
            acc[0][0] = __builtin_amdgcn_mfma_f32_16x16x32_bf16(af0, bf0, acc[0][0], 0, 0, 0);
            acc[0][1] = __builtin_amdgcn_mfma_f32_16x16x32_bf16(af0, bf1, acc[0][1], 0, 0, 0);
            acc[1][0] = __builtin_amdgcn_mfma_f32_16x16x32_bf16(af1, bf0, acc[1][0], 0, 0, 0);
            acc[1][1] = __builtin_amdgcn_mfma_f32_16x16x32_bf16(af1, bf1, acc[1][1], 0, 0, 0);
        }
    }

    // ---------- Epilogue: bias + store + fused BN stats ----------
    float* ob = out + b * COUT * 4096 + h * 64;
#pragma unroll
    for (int mt2 = 0; mt2 < 2; mt2++) {
        int ocb = (2 * m0 + mt2) * 16 + quad * 4;
#pragma unroll
        for (int r = 0; r < 4; r++) {
            int oc = ocb + r;
            float bia = b_def[oc];
            float ssum = 0.f, qsum = 0.f;
#pragma unroll
            for (int nt2 = 0; nt2 < 2; nt2++) {
                int w_ = (2 * n0 + nt2) * 16 + lo;
                float v = acc[mt2][nt2][r] + bia;
                ob[oc * 4096 + w_] = v;
                ssum += v; qsum += v * v;
            }
#pragma unroll
            for (int d = 1; d < 16; d <<= 1) {
                ssum += __shfl_xor(ssum, d, 64);
                qsum += __shfl_xor(qsum, d, 64);
            }
            if (lo == 0) {
                atomicAdd(&stat[oc], ssum);
                atomicAdd(&stat[128 + oc], qsum);
            }
        }
    }
    __syncthreads();
    if (t < 256) {
        float* g = (t < 128) ? (sums + t) : (sumsq + (t - 128));
        atomicAdd(g, stat[t]);
    }
}

__global__ void bn_finalize_k(const float* __restrict__ sums, const float* __restrict__ sumsq,
                              const float* __restrict__ gamma, const float* __restrict__ beta,
                              float* __restrict__ scsh) {
    int oc = threadIdx.x;
    const float invN = 1.f / NSTAT;
    float m = sums[oc] * invN;
    float v = fmaf(-m, m, sumsq[oc] * invN);
    float sc = gamma[oc] * rsqrtf(v + 1e-5f);
    scsh[oc]       = sc;
    scsh[128 + oc] = beta[oc] - m * sc;
}

__global__ __launch_bounds__(256) void bn_silu_k(float* __restrict__ out,
                                                 const float* __restrict__ scsh) {
    int i = blockIdx.x * 256 + threadIdx.x;
    float4 v = ((float4*)out)[i];
    int oc = ((i * 4) >> 12) & 127;
    float sc = scsh[oc], sh = scsh[128 + oc];
    float z0 = v.x * sc + sh;
    float z1 = v.y * sc + sh;
    float z2 = v.z * sc + sh;
    float z3 = v.w * sc + sh;
    v.x = z0 / (1.f + __expf(-z0));
    v.y = z1 / (1.f + __expf(-z1));
    v.z = z2 / (1.f + __expf(-z2));
    v.w = z3 / (1.f + __expf(-z3));
    ((float4*)out)[i] = v;
}

extern "C" void kernel_launch(void* const* d_in, const int* in_sizes, int n_in,
                              void* d_out, int out_size, void* d_ws, size_t ws_size,
                              hipStream_t stream) {
    const float* x     = (const float*)d_in[0];
    const float* w_off = (const float*)d_in[1];
    const float* w_def = (const float*)d_in[2];
    const float* b_def = (const float*)d_in[3];
    const float* gamma = (const float*)d_in[4];
    const float* beta  = (const float*)d_in[5];
    float* out = (float*)d_out;

    unsigned short* wb = (unsigned short*)d_ws;                       // 294912 B
    unsigned* xp  = (unsigned*)((char*)d_ws + 294912);                // 16777216 B
    float* sums   = (float*)((char*)d_ws + 294912 + 16777216);
    float* sumsq  = sums + 128;
    float* scsh   = sumsq + 128;

    hipMemsetAsync(sums, 0, 256 * sizeof(float), stream);
    prep_xp_k<<<16384, 256, 0, stream>>>(x, xp);
    repack_wdef_k<<<576, 256, 0, stream>>>(w_def, wb);
    deform_main_k<<<512, 512, 0, stream>>>(xp, w_off, wb, b_def, out, sums, sumsq);
    bn_finalize_k<<<1, 128, 0, stream>>>(sums, sumsq, gamma, beta, scsh);
    bn_silu_k<<<4096, 256, 0, stream>>>(out, scsh);
}

// Round 5
// 167.939 us; speedup vs baseline: 2.6430x; 1.2252x over previous
//
#include <hip/hip_runtime.h>
#include <math.h>

#define CIN   128
#define COUT  128
#define KKT   9
#define NSTAT 32768.0f   // B*H*W per-channel count

typedef __attribute__((ext_vector_type(8))) short bf16x8;
typedef __attribute__((ext_vector_type(4))) float f32x4;

__device__ inline unsigned short f2bf(float f) {
    union { float f; unsigned u; } v; v.f = f;
    unsigned r = v.u + 0x7fffu + ((v.u >> 16) & 1u);
    return (unsigned short)(r >> 16);
}
__device__ inline float bflo(unsigned u) { union { unsigned u; float f; } v; v.u = u << 16; return v.f; }
__device__ inline float bfhi(unsigned u) { union { unsigned u; float f; } v; v.u = u & 0xffff0000u; return v.f; }

// barrier that does NOT drain vmcnt
#define FAST_BARRIER() asm volatile("s_waitcnt lgkmcnt(0)\n\ts_barrier" ::: "memory")

// ---------------- ws layout (bytes) ----------------
// xt  : 16777216   bf16 channel-last x[b][y][x][c], stored as dword c-pairs
// wb  : 294912     [oc][kt*128+c] bf16   (main conv A)
// wob : 73728      [32 ocpad][kt*128+c] bf16 (offset conv A, rows 18..31 zero)
// sums: 512 | sumsq | (nothing else)

// Transpose x[b][c][y][w] (f32) -> xt[(b*64+y)*64 + x][c] (bf16 pairs as dwords)
__global__ __launch_bounds__(512) void prep_xt_k(const float* __restrict__ x,
                                                 unsigned* __restrict__ xt) {
    __shared__ float lt[128][65];
    const int by = blockIdx.x;          // b*64 + y
    const int b = by >> 6, y = by & 63;
    const int t = threadIdx.x, l = t & 63, g8 = t >> 6;   // g8: 0..7
    const float* xb = x + (b * 128) * 4096 + y * 64;
#pragma unroll
    for (int pass = 0; pass < 16; pass++) {
        int c = pass * 8 + g8;
        lt[c][l] = xb[c * 4096 + l];
    }
    __syncthreads();
    unsigned* xo = xt + (by * 64) * 64;   // pixel base (dwords)
#pragma unroll
    for (int pass = 0; pass < 8; pass++) {
        int w = pass * 8 + g8;
        float f0 = lt[2 * l][w], f1 = lt[2 * l + 1][w];
        xo[w * 64 + l] = (unsigned)f2bf(f0) | ((unsigned)f2bf(f1) << 16);
    }
}

__global__ __launch_bounds__(256) void repack_w_k(const float* __restrict__ w_def,
                                                  const float* __restrict__ w_off,
                                                  unsigned short* __restrict__ wb,
                                                  unsigned short* __restrict__ wob,
                                                  float* __restrict__ sums) {
    int i = blockIdx.x * 256 + threadIdx.x;
    if (i < 147456) {
        int oc = i / 1152, r = i - oc * 1152, kt = r >> 7, c = r & 127;
        wb[i] = f2bf(w_def[(oc * 128 + c) * 9 + kt]);
    } else if (i < 147456 + 36864) {
        int j = i - 147456;
        int ocp = j / 1152, r = j - ocp * 1152, kt = r >> 7, c = r & 127;
        wob[j] = (ocp < 18) ? f2bf(w_off[(ocp * 128 + c) * 9 + kt]) : (unsigned short)0;
    } else if (i < 147456 + 36864 + 256) {
        sums[i - 147456 - 36864] = 0.f;   // sums|sumsq zero (re-poisoned each launch)
    }
}

#define RB 51200
// One block per (b,h), XCD-swizzled. 512 threads = 8 waves.
__global__ __launch_bounds__(512, 4) void deform_main_k(const unsigned* __restrict__ xt,
                                                        const unsigned short* __restrict__ wb,
                                                        const unsigned short* __restrict__ wob,
                                                        const float* __restrict__ b_def,
                                                        float* __restrict__ out,
                                                        float* __restrict__ sums,
                                                        float* __restrict__ sumsq) {
    __shared__ __align__(16) unsigned char smem[RB + 4608 + 1024];
    unsigned short* xrow = (unsigned short*)smem;              // [3][66][128] bf16, 50688 B
    int*            tab  = (int*)smem;                         // [9*64][8] dwords, 18432 B (aliases xrow)
    unsigned short* samp0 = (unsigned short*)(smem + 18432);   // [64][128] bf16
    unsigned short* samp1 = (unsigned short*)(smem + 34816);
    float* offl = (float*)(smem + RB);                         // [18][64]
    float* stat = (float*)(smem + RB + 4608);                  // [256]

    const int t    = threadIdx.x;
    const int bh   = blockIdx.x;
    const int b    = bh >> 6;
    const int j_   = bh & 63;
    const int h    = ((j_ & 7) << 3) | (j_ >> 3);   // XCD-locality swizzle
    const int lane = t & 63;
    const int wv   = __builtin_amdgcn_readfirstlane(t >> 6);  // 0..7
    const int quad = lane >> 4, lo = lane & 15;
    const int l    = lane;        // c-pair index for gathers
    const int g    = lane >> 2;   // c-group of 8

    if (t < 256) stat[t] = 0.f;

    const unsigned* xtb = xt + b * 262144;   // dwords per batch image

    // ---- stage xrow: rows h-1..h+1, x = -1..64, zero-padded, swizzled ----
    for (int p = wv; p < 198; p += 8) {
        int r = p / 66, xi = p - r * 66;
        int y = h + r - 1, x = xi - 1;
        unsigned u = 0;
        if ((unsigned)y < 64u && (unsigned)x < 64u) u = xtb[(y * 64 + x) * 64 + l];
        ((unsigned*)xrow)[(r * 66 + xi) * 64 + ((g ^ (xi & 15)) << 2) + (l & 3)] = u;
    }
    __syncthreads();

    // ---- offset conv via MFMA: wave -> (mt = wv>>2, nt = wv&3), D[oc][w] ----
    {
        const int mt = wv >> 2, nt = wv & 3;
        f32x4 ao = {0.f, 0.f, 0.f, 0.f};
        const unsigned short* wrow = wob + (mt * 16 + lo) * 1152 + quad * 8;
        for (int kt = 0; kt < 9; kt++) {
            int ky = kt / 3, kx = kt - ky * 3;
            int xi = nt * 16 + lo + kx;   // xrow x-index = w + kx
#pragma unroll
            for (int ch = 0; ch < 4; ch++) {
                int gg = ch * 4 + quad;
                bf16x8 af = *(const bf16x8*)(wrow + kt * 128 + ch * 32);
                bf16x8 bf = *(const bf16x8*)(xrow + (ky * 66 + xi) * 128 + ((gg ^ (xi & 15)) << 3));
                ao = __builtin_amdgcn_mfma_f32_16x16x32_bf16(af, bf, ao, 0, 0, 0);
            }
        }
        __syncthreads();   // all waves done reading xrow
#pragma unroll
        for (int r = 0; r < 4; r++) {
            int oc = mt * 16 + quad * 4 + r;
            if (oc < 18) offl[oc * 64 + nt * 16 + lo] = ao[r];
        }
    }
    __syncthreads();   // offl ready; xrow region free for tab

    // ---- tap tables: 4 pixel addresses (dword idx) + 4 weights per (tap,w) ----
    for (int i = t; i < KKT * 64; i += 512) {
        int k = i >> 6, w2 = i & 63;
        float dy = offl[(2 * k) * 64 + w2];
        float dx = offl[(2 * k + 1) * 64 + w2];
        int ky = k / 3, kx = k - ky * 3;
        float ys = (float)(h - 1 + ky) + dy;
        float xs = (float)(w2 - 1 + kx) + dx;
        float y0f = floorf(ys), x0f = floorf(xs);
        float wyf = ys - y0f, wxf = xs - x0f;
        int iy0 = (int)y0f, ix0 = (int)x0f;
        int cy0 = min(max(iy0, 0), 63), cy1 = min(max(iy0 + 1, 0), 63);
        int px  = min(max(ix0, 0), 63), px2 = min(max(ix0 + 1, 0), 63);
        float wy0 = (iy0 >= 0 && iy0 < 64) ? (1.f - wyf) : 0.f;
        float wy1 = (iy0 + 1 >= 0 && iy0 + 1 < 64) ? wyf : 0.f;
        float wa  = (ix0 >= 0 && ix0 < 64) ? (1.f - wxf) : 0.f;
        float wbv = (ix0 + 1 >= 0 && ix0 + 1 < 64) ? wxf : 0.f;
        int base = i * 8;
        tab[base + 0] = (cy0 * 64 + px ) * 64;
        tab[base + 1] = (cy0 * 64 + px2) * 64;
        tab[base + 2] = (cy1 * 64 + px ) * 64;
        tab[base + 3] = (cy1 * 64 + px2) * 64;
        ((float*)tab)[base + 4] = wy0;
        ((float*)tab)[base + 5] = wy1;
        ((float*)tab)[base + 6] = wa;
        ((float*)tab)[base + 7] = wbv;
    }
    __syncthreads();

    // ---- main tap loop: coalesced gather + double-buffered samp + MFMA ----
    const int m0 = wv >> 1, n0 = wv & 1;
    f32x4 acc[2][2];
#pragma unroll
    for (int i = 0; i < 2; i++)
#pragma unroll
        for (int j = 0; j < 2; j++)
#pragma unroll
            for (int r = 0; r < 4; r++) acc[i][j][r] = 0.f;

    const unsigned short* wrow0 = wb + (2 * m0 * 16 + lo) * 1152 + quad * 8;
    const unsigned short* wrow1 = wrow0 + 16 * 1152;

    for (int kt = 0; kt < KKT; kt++) {
        // A-fragments for THIS tap, issued before the barrier (latency hidden by gather)
        bf16x8 af0[4], af1[4];
#pragma unroll
        for (int ch = 0; ch < 4; ch++) {
            af0[ch] = *(const bf16x8*)(wrow0 + kt * 128 + ch * 32);
            af1[ch] = *(const bf16x8*)(wrow1 + kt * 128 + ch * 32);
        }
        // gather: wave covers w = wv*8 .. wv*8+7; lane = c-pair -> coalesced dwords
        unsigned* sb = (unsigned*)((kt & 1) ? samp1 : samp0);
#pragma unroll
        for (int i = 0; i < 8; i++) {
            int w = wv * 8 + i;
            int bse = (kt * 64 + w) * 8;
            int4   ta = *(const int4*)&tab[bse];        // broadcast LDS reads
            float4 tw = *(const float4*)&tab[bse + 4];
            unsigned u00 = xtb[ta.x + l];
            unsigned u01 = xtb[ta.y + l];
            unsigned u10 = xtb[ta.z + l];
            unsigned u11 = xtb[ta.w + l];
            float e = tw.x * (tw.z * bflo(u00) + tw.w * bflo(u01)) +
                      tw.y * (tw.z * bflo(u10) + tw.w * bflo(u11));
            float o = tw.x * (tw.z * bfhi(u00) + tw.w * bfhi(u01)) +
                      tw.y * (tw.z * bfhi(u10) + tw.w * bfhi(u11));
            sb[w * 64 + ((g ^ (w & 15)) << 2) + (l & 3)] =
                (unsigned)f2bf(e) | ((unsigned)f2bf(o) << 16);
        }
        FAST_BARRIER();
        const unsigned short* sbs = (kt & 1) ? samp1 : samp0;
#pragma unroll
        for (int ch = 0; ch < 4; ch++) {
            int gg = ch * 4 + quad;
            int r0 = (2 * n0 + 0) * 16 + lo, r1 = (2 * n0 + 1) * 16 + lo;
            bf16x8 bf0 = *(const bf16x8*)(sbs + r0 * 128 + ((gg ^ lo) << 3));
            bf16x8 bf1 = *(const bf16x8*)(sbs + r1 * 128 + ((gg ^ lo) << 3));
            acc[0][0] = __builtin_amdgcn_mfma_f32_16x16x32_bf16(af0[ch], bf0, acc[0][0], 0, 0, 0);
            acc[0][1] = __builtin_amdgcn_mfma_f32_16x16x32_bf16(af0[ch], bf1, acc[0][1], 0, 0, 0);
            acc[1][0] = __builtin_amdgcn_mfma_f32_16x16x32_bf16(af1[ch], bf0, acc[1][0], 0, 0, 0);
            acc[1][1] = __builtin_amdgcn_mfma_f32_16x16x32_bf16(af1[ch], bf1, acc[1][1], 0, 0, 0);
        }
    }

    // ---- epilogue: bias + store + fused BN stats ----
    float* ob = out + b * COUT * 4096 + h * 64;
#pragma unroll
    for (int mt2 = 0; mt2 < 2; mt2++) {
        int ocb = (2 * m0 + mt2) * 16 + quad * 4;
#pragma unroll
        for (int r = 0; r < 4; r++) {
            int oc = ocb + r;
            float bia = b_def[oc];
            float ssum = 0.f, qsum = 0.f;
#pragma unroll
            for (int nt2 = 0; nt2 < 2; nt2++) {
                int w_ = (2 * n0 + nt2) * 16 + lo;
                float v = acc[mt2][nt2][r] + bia;
                ob[oc * 4096 + w_] = v;
                ssum += v; qsum += v * v;
            }
#pragma unroll
            for (int d = 1; d < 16; d <<= 1) {
                ssum += __shfl_xor(ssum, d, 64);
                qsum += __shfl_xor(qsum, d, 64);
            }
            if (lo == 0) { atomicAdd(&stat[oc], ssum); atomicAdd(&stat[128 + oc], qsum); }
        }
    }
    __syncthreads();
    if (t < 256) {
        float* gp = (t < 128) ? (sums + t) : (sumsq + (t - 128));
        atomicAdd(gp, stat[t]);
    }
}

__global__ __launch_bounds__(256) void bn_silu_k(float* __restrict__ out,
                                                 const float* __restrict__ sums,
                                                 const float* __restrict__ sumsq,
                                                 const float* __restrict__ gamma,
                                                 const float* __restrict__ beta) {
    __shared__ float sc_s[128], sh_s[128];
    int t = threadIdx.x;
    if (t < 128) {
        const float invN = 1.f / NSTAT;
        float m = sums[t] * invN;
        float v = fmaf(-m, m, sumsq[t] * invN);
        float sc = gamma[t] * rsqrtf(v + 1e-5f);
        sc_s[t] = sc;
        sh_s[t] = beta[t] - m * sc;
    }
    __syncthreads();
    int i = blockIdx.x * 256 + t;
    float4 v = ((float4*)out)[i];
    int oc = (i >> 10) & 127;
    float sc = sc_s[oc], sh = sh_s[oc];
    float z0 = v.x * sc + sh;
    float z1 = v.y * sc + sh;
    float z2 = v.z * sc + sh;
    float z3 = v.w * sc + sh;
    v.x = z0 / (1.f + __expf(-z0));
    v.y = z1 / (1.f + __expf(-z1));
    v.z = z2 / (1.f + __expf(-z2));
    v.w = z3 / (1.f + __expf(-z3));
    ((float4*)out)[i] = v;
}

extern "C" void kernel_launch(void* const* d_in, const int* in_sizes, int n_in,
                              void* d_out, int out_size, void* d_ws, size_t ws_size,
                              hipStream_t stream) {
    const float* x     = (const float*)d_in[0];
    const float* w_off = (const float*)d_in[1];
    const float* w_def = (const float*)d_in[2];
    const float* b_def = (const float*)d_in[3];
    const float* gamma = (const float*)d_in[4];
    const float* beta  = (const float*)d_in[5];
    float* out = (float*)d_out;

    unsigned*       xt   = (unsigned*)d_ws;                               // 16777216 B
    unsigned short* wb   = (unsigned short*)((char*)d_ws + 16777216);     // 294912 B
    unsigned short* wob  = (unsigned short*)((char*)d_ws + 17072128);     // 73728 B
    float*          sums = (float*)((char*)d_ws + 17145856);              // 128
    float*          sumsq = sums + 128;

    prep_xt_k<<<512, 512, 0, stream>>>(x, xt);
    repack_w_k<<<721, 256, 0, stream>>>(w_def, w_off, wb, wob, sums);
    deform_main_k<<<512, 512, 0, stream>>>(xt, wb, wob, b_def, out, sums, sumsq);
    bn_silu_k<<<4096, 256, 0, stream>>>(out, sums, sumsq, gamma, beta);
}